// Round 4
// baseline (14271.886 us; speedup 1.0000x reference)
//
#include <hip/hip_runtime.h>

#define T_STEPS 101
#define BATCH   16384
#define IN_DIM  40
#define HID     300
#define OUT_DIM 12

#define RPW 4            // rows per wave
#define WPB 8            // waves per block (512 threads)
#define RPB (RPW * WPB)  // 32 rows per block
#define NTHR (WPB * 64)

// ---- ws layout (floats) ----
// [0, 96000)         WhT[i][j] = Wh[j][i], column stride 320 (j in [300,320) = 0)
// [96000, 192000)    W2T[i][j] = W2[j][i], column stride 320
// [192000, 195600)   W3T[i][o] = W3[o][i], stride 12
#define WS_W2T 96000
#define WS_W3T 192000

// compile-time unroll helper (round-1 lesson: plain #pragma unroll bails on
// bodies with data-dependent while loops -> dynamic alloca -> scratch).
template<int I> struct ic { static constexpr int v = I; };
template<int N, int I = 0, typename F>
__device__ __forceinline__ void sfor(F&& f) {
    if constexpr (I < N) {
        f(ic<I>{});
        sfor<N, I + 1, F>(static_cast<F&&>(f));
    }
}

__global__ __launch_bounds__(256) void prep_kernel(const float* __restrict__ Wh,
                                                   const float* __restrict__ W2,
                                                   const float* __restrict__ W3,
                                                   float* __restrict__ ws) {
    int idx = blockIdx.x * 256 + threadIdx.x;
    if (idx < 96000) {
        int i = idx / 320, j = idx % 320;
        ws[idx] = (j < HID) ? Wh[j * HID + i] : 0.f;
    } else if (idx < 192000) {
        int k = idx - 96000;
        int i = k / 320, j = k % 320;
        ws[idx] = (j < HID) ? W2[j * HID + i] : 0.f;
    } else if (idx < 195600) {
        int k = idx - 192000;
        int i = k / OUT_DIM, j = k % OUT_DIM;
        ws[idx] = W3[j * HID + i];
    }
}

// 512 thr, min 4 waves/EU -> VGPR cap 128; per-thread demand ~110 (RPW=4).
// LDS 61.7 KB -> 2 blocks/CU -> 16 waves/CU.
__global__ __launch_bounds__(NTHR, 4) void snn_kernel(
    const float* __restrict__ x,    // [T, B, 40]
    const float* __restrict__ W1,   // [300, 40]
    const float* __restrict__ b1,   // [300]
    const float* __restrict__ bh,   // [300]
    const float* __restrict__ b2,   // [300]
    const float* __restrict__ b3,   // [12]
    const float* __restrict__ ws,   // transposed/padded weights
    float* __restrict__ out)        // [B, 12]
{
    // w1c[kc][j][c] = W1[j][4*kc+c], j stride 304; reads reach j<320 (tail
    // lanes, ballot-masked) so alloc covers (9*304+319)*4+4 floats.
    __shared__ float w1c[12224];                 // 48896 B
    __shared__ float xb[2][RPB][IN_DIM];         // 10240 B, per-wave dbuf
    __shared__ float b1hL[320];                  // b1 + bh (pad 0)
    __shared__ float b2rL[320];                  // b2 (pad 0)

    const int tid  = threadIdx.x;
    const int lane = tid & 63;
    const int wv   = __builtin_amdgcn_readfirstlane(tid >> 6);
    const int row0 = blockIdx.x * RPB + wv * RPW;   // this wave's first row

    // ---- stage W1 (304 rows x 10 chunks) + zero the tail scratch ----
    for (int idx = tid; idx < 3040; idx += NTHR) {
        int kc = idx % 10;
        int j  = idx / 10;
        float4 v;
        if (j < HID) v = *(const float4*)(W1 + j * IN_DIM + kc * 4);
        else         v = make_float4(0.f, 0.f, 0.f, 0.f);
        *(float4*)(w1c + (kc * 304 + j) * 4) = v;
    }
    for (int idx = tid; idx < 64; idx += NTHR) w1c[12160 + idx] = 0.f;
    for (int j = tid; j < 320; j += NTHR) {
        b1hL[j] = (j < HID) ? (b1[j] + bh[j]) : 0.f;
        b2rL[j] = (j < HID) ? b2[j] : 0.f;
    }

    // ---- per-wave x preload (t=0): 4 rows x 40 floats = 40 float4 ----
    float4 xreg = make_float4(0.f, 0.f, 0.f, 0.f);
    if (lane < 40) xreg = ((const float4*)(x + (size_t)row0 * IN_DIM))[lane];

    // spike masks live in SGPRs (ballot results are wave-uniform)
    unsigned long long mskr[RPW][5];
    float v1[RPW][5], v2[RPW][5], oar[RPW];
    sfor<RPW>([&](auto rc) {
        constexpr int r = decltype(rc)::v;
        oar[r] = 0.f;
        sfor<5>([&](auto uc) {
            constexpr int u = decltype(uc)::v;
            mskr[r][u] = 0ull; v1[r][u] = 0.f; v2[r][u] = 0.f;
        });
    });
    float b3r = (lane < OUT_DIM) ? b3[lane] : 0.f;

    const float* WhT = ws;
    const float* W2T = ws + WS_W2T;
    const float* W3T = ws + WS_W3T;

    if (lane < 40) ((float4*)&xb[0][wv * RPW][0])[lane] = xreg;
    __syncthreads();

    const unsigned long long TAILMASK = (1ull << 44) - 1ull;  // 44 valid lanes at u=4

    for (int t = 0; t < T_STEPS; ++t) {
        // issue next step's x load early (consumed by ds_write at step end)
        if (t + 1 < T_STEPS && lane < 40)
            xreg = ((const float4*)(x + ((size_t)(t + 1) * BATCH + row0) * IN_DIM))[lane];

        const float(*xc)[IN_DIM] = xb[t & 1];

        // ---- h1 = x @ W1^T + (b1 + bh) ----
        float acc[RPW][5];
        {
            float bini[5];
            sfor<5>([&](auto uc) {
                constexpr int u = decltype(uc)::v;
                bini[u] = b1hL[lane + 64 * u];
            });
            sfor<RPW>([&](auto rc) {
                constexpr int r = decltype(rc)::v;
                sfor<5>([&](auto uc) {
                    constexpr int u = decltype(uc)::v;
                    acc[r][u] = bini[u];
                });
            });
        }

        sfor<10>([&](auto kcc) {
            constexpr int kc = decltype(kcc)::v;
            float4 w[5];
            sfor<5>([&](auto uc) {
                constexpr int u = decltype(uc)::v;
                w[u] = *(const float4*)(w1c + (kc * 304 + lane + 64 * u) * 4);
            });
            sfor<RPW>([&](auto rc) {
                constexpr int r = decltype(rc)::v;
                float4 xv = *(const float4*)(&xc[wv * RPW + r][kc * 4]);  // broadcast
                sfor<5>([&](auto uc) {
                    constexpr int u = decltype(uc)::v;
                    float a = acc[r][u];
                    a = fmaf(w[u].x, xv.x, a);
                    a = fmaf(w[u].y, xv.y, a);
                    a = fmaf(w[u].z, xv.z, a);
                    a = fmaf(w[u].w, xv.w, a);
                    acc[r][u] = a;
                });
            });
        });

        // ---- per-row LIF dynamics ----
        sfor<RPW>([&](auto rc) {
            constexpr int r = decltype(rc)::v;

            // recurrent input: y_{t-1} @ Wh^T (scalar-driven sparse gather)
            sfor<5>([&](auto u2c) {
                constexpr int u2 = decltype(u2c)::v;
                unsigned long long m = mskr[r][u2];
                while (m) {
                    int b = __builtin_ctzll(m);
                    m &= m - 1;
                    const float* col = WhT + (u2 * 64 + b) * 320;  // scalar base
                    sfor<5>([&](auto uc) {
                        constexpr int u = decltype(uc)::v;
                        acc[r][u] += col[lane + 64 * u];
                    });
                }
            });

            // LIF layer 1: v += (cur - v)/2 ; spike ; hard reset
            unsigned long long nm[5];
            sfor<5>([&](auto uc) {
                constexpr int u = decltype(uc)::v;
                float v = v1[r][u];
                v = v + (acc[r][u] - v) * 0.5f;
                bool s = (v >= 1.0f);
                v1[r][u] = s ? 0.f : v;
                nm[u] = __ballot(s);
            });
            nm[4] &= TAILMASK;
            sfor<5>([&](auto uc) {
                constexpr int u = decltype(uc)::v;
                mskr[r][u] = nm[u];
            });

            // layer 2: cur2 = y @ W2^T + b2 (sparse)
            float c2[5];
            sfor<5>([&](auto uc) {
                constexpr int u = decltype(uc)::v;
                c2[u] = b2rL[lane + 64 * u];
            });
            sfor<5>([&](auto u2c) {
                constexpr int u2 = decltype(u2c)::v;
                unsigned long long m = nm[u2];
                while (m) {
                    int b = __builtin_ctzll(m);
                    m &= m - 1;
                    const float* col = W2T + (u2 * 64 + b) * 320;
                    sfor<5>([&](auto uc) {
                        constexpr int u = decltype(uc)::v;
                        c2[u] += col[lane + 64 * u];
                    });
                }
            });

            // LIF layer 2 + output accumulation (s2 spikes are very rare)
            unsigned long long sm[5];
            sfor<5>([&](auto uc) {
                constexpr int u = decltype(uc)::v;
                float v = v2[r][u];
                v = v + (c2[u] - v) * 0.5f;
                bool s = (v >= 1.0f);
                v2[r][u] = s ? 0.f : v;
                sm[u] = __ballot(s);
            });
            sm[4] &= TAILMASK;
            sfor<5>([&](auto u2c) {
                constexpr int u2 = decltype(u2c)::v;
                unsigned long long m = sm[u2];
                while (m) {
                    int b = __builtin_ctzll(m);
                    m &= m - 1;
                    if (lane < OUT_DIM)
                        oar[r] += W3T[(u2 * 64 + b) * OUT_DIM + lane];
                }
            });
        });

        // write next step's x into the other buffer (wave-private, no barrier)
        if (t + 1 < T_STEPS && lane < 40)
            ((float4*)&xb[(t + 1) & 1][wv * RPW][0])[lane] = xreg;
    }

    // ---- epilogue: out = oar + 101 * b3, straight from registers ----
    sfor<RPW>([&](auto rc) {
        constexpr int r = decltype(rc)::v;
        if (lane < OUT_DIM)
            out[(size_t)(row0 + r) * OUT_DIM + lane] = oar[r] + 101.0f * b3r;
    });
}

extern "C" void kernel_launch(void* const* d_in, const int* in_sizes, int n_in,
                              void* d_out, int out_size, void* d_ws, size_t ws_size,
                              hipStream_t stream) {
    const float* x  = (const float*)d_in[0];
    const float* W1 = (const float*)d_in[1];
    const float* b1 = (const float*)d_in[2];
    const float* Wh = (const float*)d_in[3];
    const float* bh = (const float*)d_in[4];
    const float* W2 = (const float*)d_in[5];
    const float* b2 = (const float*)d_in[6];
    const float* W3 = (const float*)d_in[7];
    const float* b3 = (const float*)d_in[8];
    float* out = (float*)d_out;
    float* ws  = (float*)d_ws;

    prep_kernel<<<(195600 + 255) / 256, 256, 0, stream>>>(Wh, W2, W3, ws);
    snn_kernel<<<BATCH / RPB, NTHR, 0, stream>>>(x, W1, b1, bh, b2, b3, ws, out);
}